// Round 1
// baseline (331.125 us; speedup 1.0000x reference)
//
#include <hip/hip_runtime.h>

typedef unsigned short u16;
typedef __bf16 bf16x8 __attribute__((ext_vector_type(8)));
typedef float f32x4 __attribute__((ext_vector_type(4)));
typedef u16 u16x4 __attribute__((ext_vector_type(4)));

#define DEVI static __device__ __forceinline__

DEVI u16 f2bf(float f){
  unsigned u = __float_as_uint(f);
  u += 0x7FFFu + ((u >> 16) & 1u);
  return (u16)(u >> 16);
}

DEVI f32x4 mfma16(bf16x8 a, bf16x8 b, f32x4 c){
  return __builtin_amdgcn_mfma_f32_16x16x32_bf16(a, b, c, 0, 0, 0);
}

DEVI void gld16(u16* lds, const u16* g){
  __builtin_amdgcn_global_load_lds(
      (const __attribute__((address_space(1))) void*)g,
      (__attribute__((address_space(3))) void*)lds, 16, 0, 0);
}

// ---------------- fp32 -> bf16 convert ----------------
__global__ void cvt_bf16(const float* __restrict__ s, u16* __restrict__ d, int n4){
  int i = blockIdx.x * blockDim.x + threadIdx.x;
  int stride = gridDim.x * blockDim.x;
  for (; i < n4; i += stride){
    float4 v = *(const float4*)(s + (size_t)i * 4);
    u16x4 o = { f2bf(v.x), f2bf(v.y), f2bf(v.z), f2bf(v.w) };
    *(u16x4*)(d + (size_t)i * 4) = o;
  }
}

// ---------------- GEMM: C = A * Bm^T + bias ----------------
// A[M,K] bf16 row-major, Bm[N,K] bf16 row-major. K = 1024.
// 128x128 tile, BK=32, 256 threads (4 waves, each 64x64).
// MODE 0: QKV epilogue (split-store Q,K row-major; V transposed per-window)
// MODE 1: fp32 store to Cf (N=1024) + bias.
template<int MODE>
__global__ __launch_bounds__(256)
void gemm_bt(const u16* __restrict__ A, const u16* __restrict__ Bm,
             const float* __restrict__ bias,
             u16* __restrict__ Qws, u16* __restrict__ Kws, u16* __restrict__ Vtws,
             float* __restrict__ Cf)
{
  constexpr int K = 1024;
  __shared__ __align__(16) u16 As[128 * 32];
  __shared__ __align__(16) u16 Bs[128 * 32];
  const int t = threadIdx.x;
  const int w = t >> 6, l = t & 63, g = l >> 4, r16 = l & 15;
  const int row0 = blockIdx.y * 128, col0 = blockIdx.x * 128;
  const int wr = (w >> 1) * 64, wc = (w & 1) * 64;

  const f32x4 zero = {0.f, 0.f, 0.f, 0.f};
  f32x4 acc[4][4];
#pragma unroll
  for (int m = 0; m < 4; ++m)
#pragma unroll
    for (int n = 0; n < 4; ++n) acc[m][n] = zero;

  const u16* Ag = A + (size_t)(row0 + (t >> 2)) * K + (t & 3) * 8;
  const u16* Bg = Bm + (size_t)(col0 + (t >> 2)) * K + (t & 3) * 8;
  u16* As0 = As + (w << 9);   // wave-uniform LDS staging base
  u16* Bs0 = Bs + (w << 9);

  for (int kt = 0; kt < K; kt += 32){
    gld16(As0,        Ag + kt);
    gld16(As0 + 2048, Ag + (size_t)64 * K + kt);
    gld16(Bs0,        Bg + kt);
    gld16(Bs0 + 2048, Bg + (size_t)64 * K + kt);
    __syncthreads();
    bf16x8 af[4], bfr[4];
#pragma unroll
    for (int m = 0; m < 4; ++m)
      af[m] = *(const bf16x8*)(As + (wr + m * 16 + r16) * 32 + g * 8);
#pragma unroll
    for (int n = 0; n < 4; ++n)
      bfr[n] = *(const bf16x8*)(Bs + (wc + n * 16 + r16) * 32 + g * 8);
#pragma unroll
    for (int m = 0; m < 4; ++m)
#pragma unroll
      for (int n = 0; n < 4; ++n)
        acc[m][n] = mfma16(af[m], bfr[n], acc[m][n]);
    __syncthreads();
  }

  float bv[4];
#pragma unroll
  for (int nb = 0; nb < 4; ++nb) bv[nb] = bias[col0 + wc + nb * 16 + r16];

  if (MODE == 1){
#pragma unroll
    for (int m = 0; m < 4; ++m){
      int row = row0 + wr + m * 16 + g * 4;
#pragma unroll
      for (int nb = 0; nb < 4; ++nb){
        int n = col0 + wc + nb * 16 + r16;
#pragma unroll
        for (int j = 0; j < 4; ++j)
          Cf[(size_t)(row + j) * 1024 + n] = acc[m][nb][j] + bv[nb];
      }
    }
  } else {
    const int regn = col0 >> 10;   // uniform per block: 0=Q 1=K 2=V
    if (regn == 0){
#pragma unroll
      for (int m = 0; m < 4; ++m){
        int row = row0 + wr + m * 16 + g * 4;
#pragma unroll
        for (int nb = 0; nb < 4; ++nb){
          int n = col0 + wc + nb * 16 + r16;
#pragma unroll
          for (int j = 0; j < 4; ++j)
            Qws[(size_t)(row + j) * 1024 + n] = f2bf(acc[m][nb][j] + bv[nb]);
        }
      }
    } else if (regn == 1){
#pragma unroll
      for (int m = 0; m < 4; ++m){
        int row = row0 + wr + m * 16 + g * 4;
#pragma unroll
        for (int nb = 0; nb < 4; ++nb){
          int n = col0 + wc + nb * 16 + r16 - 1024;
#pragma unroll
          for (int j = 0; j < 4; ++j)
            Kws[(size_t)(row + j) * 1024 + n] = f2bf(acc[m][nb][j] + bv[nb]);
        }
      }
    } else {
      // V: store transposed per window: Vt[win][d][r], win=((b*16+h)*16+wd)
#pragma unroll
      for (int m = 0; m < 4; ++m){
        int row = row0 + wr + m * 16 + g * 4;
        int bb = row >> 12, s = row & 4095;
        int wdw = s >> 8, r = s & 255;      // r multiple of 4
#pragma unroll
        for (int nb = 0; nb < 4; ++nb){
          int n2 = col0 + wc + nb * 16 + r16 - 2048;
          int hh = n2 >> 6, d = n2 & 63;
          int winw = (bb * 16 + hh) * 16 + wdw;
          u16x4 pk;
#pragma unroll
          for (int j = 0; j < 4; ++j) pk[j] = f2bf(acc[m][nb][j] + bv[nb]);
          *(u16x4*)(Vtws + (size_t)winw * 16384 + d * 256 + r) = pk;
        }
      }
    }
  }
}

// ---------------- windowed attention ----------------
// 1 block = 1 (b,h,window). 4 waves x 64 q-rows. Online softmax over 4
// key-chunks of 64. K chunk LDS [64 r][64 d], V chunk LDS [64 d][64 r]
// (pre-transposed in global by GEMM1), both XOR-swizzled (slot ^= row&7)
// via pre-swizzled global_load_lds source. P round-trips through
// wave-private swizzled LDS to convert D-layout -> A-layout.
__global__ __launch_bounds__(256, 1)
void attn_win(const u16* __restrict__ Q, const u16* __restrict__ Kws,
              const u16* __restrict__ Vt, u16* __restrict__ Oo)
{
  __shared__ __align__(16) u16 Kl[64 * 64];
  __shared__ __align__(16) u16 Vl[64 * 64];
  __shared__ __align__(16) u16 Pl[4 * 64 * 64];
  const int t = threadIdx.x;
  const int wv = t >> 6, l = t & 63, g = l >> 4, r16 = l & 15;
  const int win = blockIdx.x;
  const int b = win >> 8, h = (win >> 4) & 15, wd = win & 15;
  const int s0 = b * 4096 + wd * 256;
  const size_t vwin = (size_t)win * 16384;
  const int r0 = t >> 3, sl = t & 7;
  const int swz = sl ^ (r0 & 7);

  bf16x8 aq[4][2];
#pragma unroll
  for (int qm = 0; qm < 4; ++qm)
#pragma unroll
    for (int kk = 0; kk < 2; ++kk)
      aq[qm][kk] = *(const bf16x8*)(Q + (size_t)(s0 + wv * 64 + qm * 16 + r16) * 1024
                                      + h * 64 + kk * 32 + g * 8);

  const f32x4 zero = {0.f, 0.f, 0.f, 0.f};
  f32x4 o[4][4];
  float mrun[4][4], lrun[4][4];
#pragma unroll
  for (int qm = 0; qm < 4; ++qm)
#pragma unroll
    for (int j = 0; j < 4; ++j){ mrun[qm][j] = -1e30f; lrun[qm][j] = 0.f; }
#pragma unroll
  for (int qm = 0; qm < 4; ++qm)
#pragma unroll
    for (int nd = 0; nd < 4; ++nd) o[qm][nd] = zero;

  const float cl2 = 0.125f * 1.44269504f;   // scale * log2(e)

  for (int kc = 0; kc < 4; ++kc){
    __syncthreads();   // prev-chunk readers done before LDS overwrite
    {
      const u16* ksrc = Kws + (size_t)(s0 + kc * 64 + r0) * 1024 + h * 64 + swz * 8;
      gld16(Kl + (wv << 9),        ksrc);
      gld16(Kl + 2048 + (wv << 9), ksrc + (size_t)32 * 1024);
      const u16* vsrc = Vt + vwin + (size_t)r0 * 256 + kc * 64 + swz * 8;
      gld16(Vl + (wv << 9),        vsrc);
      gld16(Vl + 2048 + (wv << 9), vsrc + 32 * 256);
    }
    __syncthreads();

    // QK^T for this 64-key chunk
    f32x4 sc[4][4];
#pragma unroll
    for (int qm = 0; qm < 4; ++qm)
#pragma unroll
      for (int nb = 0; nb < 4; ++nb) sc[qm][nb] = zero;
#pragma unroll
    for (int kk = 0; kk < 2; ++kk){
      bf16x8 kb[4];
#pragma unroll
      for (int nb = 0; nb < 4; ++nb){
        int r = nb * 16 + r16;
        kb[nb] = *(const bf16x8*)((const char*)Kl + r * 128
                                  + ((((kk << 2) | g) ^ (r16 & 7)) << 4));
      }
#pragma unroll
      for (int qm = 0; qm < 4; ++qm)
#pragma unroll
        for (int nb = 0; nb < 4; ++nb)
          sc[qm][nb] = mfma16(aq[qm][kk], kb[nb], sc[qm][nb]);
    }

    // online softmax + P -> LDS (bf16, swizzled)
#pragma unroll
    for (int qm = 0; qm < 4; ++qm){
#pragma unroll
      for (int j = 0; j < 4; ++j){
        float cm = fmaxf(fmaxf(sc[qm][0][j], sc[qm][1][j]),
                         fmaxf(sc[qm][2][j], sc[qm][3][j]));
        cm = fmaxf(cm, __shfl_xor(cm, 1));
        cm = fmaxf(cm, __shfl_xor(cm, 2));
        cm = fmaxf(cm, __shfl_xor(cm, 4));
        cm = fmaxf(cm, __shfl_xor(cm, 8));
        float mn = fmaxf(mrun[qm][j], cm);
        float fsc = __builtin_amdgcn_exp2f((mrun[qm][j] - mn) * cl2);
        mrun[qm][j] = mn;
        float rs = 0.f;
#pragma unroll
        for (int nb = 0; nb < 4; ++nb){
          float p = __builtin_amdgcn_exp2f((sc[qm][nb][j] - mn) * cl2);
          sc[qm][nb][j] = p;
          rs += p;
        }
        rs += __shfl_xor(rs, 1);
        rs += __shfl_xor(rs, 2);
        rs += __shfl_xor(rs, 4);
        rs += __shfl_xor(rs, 8);
        lrun[qm][j] = lrun[qm][j] * fsc + rs;
#pragma unroll
        for (int nd = 0; nd < 4; ++nd) o[qm][nd][j] *= fsc;
        int q = qm * 16 + g * 4 + j;
        char* pbase = (char*)Pl + (wv << 13) + q * 128;
#pragma unroll
        for (int nb = 0; nb < 4; ++nb){
          int k = nb * 16 + r16;
          *(u16*)(pbase + ((k & 7) * 2 + (((k >> 3) ^ (q & 7)) << 4))) = f2bf(sc[qm][nb][j]);
        }
      }
    }

    // PV: O += P[64q x 64k] * V[64k x 64d]
#pragma unroll
    for (int kc32 = 0; kc32 < 2; ++kc32){
      bf16x8 pa[4], vb[4];
#pragma unroll
      for (int qm = 0; qm < 4; ++qm){
        int q = qm * 16 + r16;
        pa[qm] = *(const bf16x8*)((const char*)Pl + (wv << 13) + q * 128
                                  + ((((kc32 << 2) | g) ^ (r16 & 7)) << 4));
      }
#pragma unroll
      for (int nd = 0; nd < 4; ++nd){
        int dd = nd * 16 + r16;
        vb[nd] = *(const bf16x8*)((const char*)Vl + dd * 128
                                  + ((((kc32 << 2) | g) ^ (r16 & 7)) << 4));
      }
#pragma unroll
      for (int qm = 0; qm < 4; ++qm)
#pragma unroll
        for (int nd = 0; nd < 4; ++nd)
          o[qm][nd] = mfma16(pa[qm], vb[nd], o[qm][nd]);
    }
  }

  // normalize + store (bf16, [B,S,H*D] layout)
#pragma unroll
  for (int qm = 0; qm < 4; ++qm){
#pragma unroll
    for (int j = 0; j < 4; ++j){
      float inv = 1.f / lrun[qm][j];
      int row = s0 + wv * 64 + qm * 16 + g * 4 + j;
#pragma unroll
      for (int nd = 0; nd < 4; ++nd)
        Oo[(size_t)row * 1024 + h * 64 + nd * 16 + r16] = f2bf(o[qm][nd][j] * inv);
    }
  }
}

// ---------------- launch ----------------
extern "C" void kernel_launch(void* const* d_in, const int* in_sizes, int n_in,
                              void* d_out, int out_size, void* d_ws, size_t ws_size,
                              hipStream_t stream)
{
  (void)in_sizes; (void)n_in; (void)out_size; (void)ws_size;
  const float* x  = (const float*)d_in[0];
  const float* Wq = (const float*)d_in[1];
  const float* bq = (const float*)d_in[2];
  const float* Wo = (const float*)d_in[3];
  const float* bo = (const float*)d_in[4];

  char* ws = (char*)d_ws;
  const size_t SZ = (size_t)16384 * 1024 * 2;          // 33.5 MB
  u16* xb  = (u16*)(ws);                               // x bf16, later reused for attn out
  u16* Vt  = (u16*)(ws + SZ);                          // V transposed per window
  u16* wqb = (u16*)(ws + 2 * SZ);                      // W_qkv bf16 (6.29 MB)
  u16* wob = (u16*)(ws + 2 * SZ + 6291456);            // W_out bf16 (2.1 MB)
  // Q,K staged in d_out (dead until final GEMM overwrites it)
  u16* Qws = (u16*)d_out;
  u16* Kws = (u16*)d_out + (size_t)16384 * 1024;

  cvt_bf16<<<2048, 256, 0, stream>>>(x,  xb,  16777216 / 4);
  cvt_bf16<<<768,  256, 0, stream>>>(Wq, wqb, 3145728 / 4);
  cvt_bf16<<<256,  256, 0, stream>>>(Wo, wob, 1048576 / 4);

  gemm_bt<0><<<dim3(24, 128), 256, 0, stream>>>(xb, wqb, bq, Qws, Kws, Vt, nullptr);

  attn_win<<<1024, 256, 0, stream>>>(Qws, Kws, Vt, xb);

  gemm_bt<1><<<dim3(8, 128), 256, 0, stream>>>(xb, wob, bo,
                                               nullptr, nullptr, nullptr,
                                               (float*)d_out);
}

// Round 2
// 295.352 us; speedup vs baseline: 1.1211x; 1.1211x over previous
//
#include <hip/hip_runtime.h>

typedef unsigned short u16;
typedef __bf16 bf16x8 __attribute__((ext_vector_type(8)));
typedef float f32x4 __attribute__((ext_vector_type(4)));
typedef u16 u16x4 __attribute__((ext_vector_type(4)));

#define DEVI static __device__ __forceinline__

DEVI u16 f2bf(float f){
  unsigned u = __float_as_uint(f);
  u += 0x7FFFu + ((u >> 16) & 1u);
  return (u16)(u >> 16);
}

DEVI f32x4 mfma16(bf16x8 a, bf16x8 b, f32x4 c){
  return __builtin_amdgcn_mfma_f32_16x16x32_bf16(a, b, c, 0, 0, 0);
}

DEVI void gld16(u16* lds, const u16* g){
  __builtin_amdgcn_global_load_lds(
      (const __attribute__((address_space(1))) void*)g,
      (__attribute__((address_space(3))) void*)lds, 16, 0, 0);
}

// ---------------- fp32 -> bf16 convert ----------------
__global__ void cvt_bf16(const float* __restrict__ s, u16* __restrict__ d, int n4){
  int i = blockIdx.x * blockDim.x + threadIdx.x;
  int stride = gridDim.x * blockDim.x;
  for (; i < n4; i += stride){
    float4 v = *(const float4*)(s + (size_t)i * 4);
    u16x4 o = { f2bf(v.x), f2bf(v.y), f2bf(v.z), f2bf(v.w) };
    *(u16x4*)(d + (size_t)i * 4) = o;
  }
}

// ---------------- GEMM: C = A * Bm^T + bias ----------------
// 256x256 tile, BK=32, 512 threads (8 waves as 2Mx4N, each 128x64 out).
// Triple-buffered LDS (96 KiB), counted vmcnt(8) pipeline: stage tile t+2
// while computing tile t (disjoint buffers -> race-free), raw s_barrier
// (no vmcnt(0) drain in main loop). T2 swizzle: linear gld_lds dest +
// inverse-swizzled global source, swizzled ds_read.
// MODE 0: QKV epilogue (Q,K row-major bf16; V transposed per-window)
// MODE 1: fp32 store + bias.
template<int MODE>
__global__ __launch_bounds__(512, 2)
void gemm_bt(const u16* __restrict__ A, const u16* __restrict__ Bm,
             const float* __restrict__ bias,
             u16* __restrict__ Qws, u16* __restrict__ Kws, u16* __restrict__ Vtws,
             float* __restrict__ Cf)
{
  constexpr int K = 1024;
  constexpr int NT = K / 32;                 // 32 K-tiles
  __shared__ __align__(16) u16 lds[3 * 16384];   // 96 KiB: 3 x (A 8192 + B 8192)
  const int t = threadIdx.x;
  const int w = t >> 6, l = t & 63, g = l >> 4, r16 = l & 15;
  const int wm = w >> 2, wn = w & 3;
  const int row0 = blockIdx.y * 256, col0 = blockIdx.x * 256;

  const f32x4 zero = {0.f, 0.f, 0.f, 0.f};
  f32x4 acc[8][4];
#pragma unroll
  for (int m = 0; m < 8; ++m)
#pragma unroll
    for (int n = 0; n < 4; ++n) acc[m][n] = zero;

  // ---- staging (write side): thread t covers row r=t>>2 (and r+128),
  // LDS linear slot s=t&3; fetch global slot s ^ fx(r) so that a
  // fx-swizzled READ sees the right data (rule 21: both sides).
  const int r = t >> 2;
  const int fxr = (r ^ (r >> 2)) & 3;
  const int sp = (t ^ fxr) & 3;
  const u16* Ag0 = A + (size_t)(row0 + r) * K + sp * 8;
  const u16* Ag1 = A + (size_t)(row0 + 128 + r) * K + sp * 8;
  const u16* Bg0 = Bm + (size_t)(col0 + r) * K + sp * 8;
  const u16* Bg1 = Bm + (size_t)(col0 + 128 + r) * K + sp * 8;
  u16* ldsw = lds + w * 512;                 // wave-uniform dest base

  auto STAGE = [&](int kt, int buf){
    u16* dst = ldsw + buf * 16384;
    gld16(dst,         Ag0 + kt);
    gld16(dst + 4096,  Ag1 + kt);
    gld16(dst + 8192,  Bg0 + kt);
    gld16(dst + 12288, Bg1 + kt);
  };

  // ---- read side: frag row -> byte = row*64 + ((g ^ fx(row))&3)*16
  const int fxl = (r16 ^ (r16 >> 2)) & 3;
  const int slot = ((g ^ fxl) & 3) * 8;      // u16 offset within row
  const int aoff = (wm * 128 + r16) * 32 + slot;
  const int boff = 8192 + (wn * 64 + r16) * 32 + slot;

  auto COMPUTE = [&](int buf){
    const u16* base = lds + buf * 16384;
    bf16x8 af[8], bfr[4];
#pragma unroll
    for (int m = 0; m < 8; ++m)
      af[m] = *(const bf16x8*)(base + aoff + m * 512);
#pragma unroll
    for (int n = 0; n < 4; ++n)
      bfr[n] = *(const bf16x8*)(base + boff + n * 512);
    __builtin_amdgcn_s_setprio(1);
#pragma unroll
    for (int m = 0; m < 8; ++m)
#pragma unroll
      for (int n = 0; n < 4; ++n)
        acc[m][n] = mfma16(af[m], bfr[n], acc[m][n]);
    __builtin_amdgcn_s_setprio(0);
  };

  STAGE(0, 0);
  STAGE(32, 1);
  int cbuf = 0, sbuf = 2;
  for (int tt = 0; tt < NT - 2; ++tt){
    STAGE((tt + 2) * 32, sbuf);
    asm volatile("s_waitcnt vmcnt(8)" ::: "memory");
    __builtin_amdgcn_s_barrier();
    asm volatile("" ::: "memory");
    COMPUTE(cbuf);
    asm volatile("" ::: "memory");
    __builtin_amdgcn_s_barrier();
    cbuf = (cbuf == 2) ? 0 : cbuf + 1;
    sbuf = (sbuf == 2) ? 0 : sbuf + 1;
  }
  asm volatile("s_waitcnt vmcnt(4)" ::: "memory");
  __builtin_amdgcn_s_barrier();
  asm volatile("" ::: "memory");
  COMPUTE(cbuf);
  asm volatile("" ::: "memory");
  __builtin_amdgcn_s_barrier();
  cbuf = (cbuf == 2) ? 0 : cbuf + 1;
  asm volatile("s_waitcnt vmcnt(0)" ::: "memory");
  __builtin_amdgcn_s_barrier();
  asm volatile("" ::: "memory");
  COMPUTE(cbuf);

  // ---- epilogue ----
  float bv[4];
#pragma unroll
  for (int nb = 0; nb < 4; ++nb) bv[nb] = bias[col0 + wn * 64 + nb * 16 + r16];

  if (MODE == 1){
#pragma unroll
    for (int m = 0; m < 8; ++m){
      int row = row0 + wm * 128 + m * 16 + g * 4;
#pragma unroll
      for (int nb = 0; nb < 4; ++nb){
        int n = col0 + wn * 64 + nb * 16 + r16;
#pragma unroll
        for (int j = 0; j < 4; ++j)
          Cf[(size_t)(row + j) * 1024 + n] = acc[m][nb][j] + bv[nb];
      }
    }
  } else {
    const int regn = col0 >> 10;   // uniform per block: 0=Q 1=K 2=V
    if (regn == 0){
#pragma unroll
      for (int m = 0; m < 8; ++m){
        int row = row0 + wm * 128 + m * 16 + g * 4;
#pragma unroll
        for (int nb = 0; nb < 4; ++nb){
          int n = col0 + wn * 64 + nb * 16 + r16;
#pragma unroll
          for (int j = 0; j < 4; ++j)
            Qws[(size_t)(row + j) * 1024 + n] = f2bf(acc[m][nb][j] + bv[nb]);
        }
      }
    } else if (regn == 1){
#pragma unroll
      for (int m = 0; m < 8; ++m){
        int row = row0 + wm * 128 + m * 16 + g * 4;
#pragma unroll
        for (int nb = 0; nb < 4; ++nb){
          int n = col0 + wn * 64 + nb * 16 + r16 - 1024;
#pragma unroll
          for (int j = 0; j < 4; ++j)
            Kws[(size_t)(row + j) * 1024 + n] = f2bf(acc[m][nb][j] + bv[nb]);
        }
      }
    } else {
      // V: store transposed per window: Vt[win][d][rr], win=((b*16+h)*16+wd)
#pragma unroll
      for (int m = 0; m < 8; ++m){
        int row = row0 + wm * 128 + m * 16 + g * 4;
        int bb = row >> 12, s = row & 4095;
        int wdw = s >> 8, rr = s & 255;      // rr multiple of 4
#pragma unroll
        for (int nb = 0; nb < 4; ++nb){
          int n2 = col0 + wn * 64 + nb * 16 + r16 - 2048;
          int hh = n2 >> 6, d = n2 & 63;
          int winw = (bb * 16 + hh) * 16 + wdw;
          u16x4 pk;
#pragma unroll
          for (int j = 0; j < 4; ++j) pk[j] = f2bf(acc[m][nb][j] + bv[nb]);
          *(u16x4*)(Vtws + (size_t)winw * 16384 + d * 256 + rr) = pk;
        }
      }
    }
  }
}

// ---------------- windowed attention ----------------
// 1 block = 1 (b,h,window). 4 waves x 64 q-rows. Online softmax over 4
// key-chunks of 64. K chunk LDS [64 r][64 d], V chunk LDS [64 d][64 r]
// (pre-transposed in global by GEMM1), both XOR-swizzled via pre-swizzled
// global_load_lds source. P round-trips through wave-private swizzled LDS.
__global__ __launch_bounds__(256, 1)
void attn_win(const u16* __restrict__ Q, const u16* __restrict__ Kws,
              const u16* __restrict__ Vt, u16* __restrict__ Oo)
{
  __shared__ __align__(16) u16 Kl[64 * 64];
  __shared__ __align__(16) u16 Vl[64 * 64];
  __shared__ __align__(16) u16 Pl[4 * 64 * 64];
  const int t = threadIdx.x;
  const int wv = t >> 6, l = t & 63, g = l >> 4, r16 = l & 15;
  const int win = blockIdx.x;
  const int b = win >> 8, h = (win >> 4) & 15, wd = win & 15;
  const int s0 = b * 4096 + wd * 256;
  const size_t vwin = (size_t)win * 16384;
  const int r0 = t >> 3, sl = t & 7;
  const int swz = sl ^ (r0 & 7);

  bf16x8 aq[4][2];
#pragma unroll
  for (int qm = 0; qm < 4; ++qm)
#pragma unroll
    for (int kk = 0; kk < 2; ++kk)
      aq[qm][kk] = *(const bf16x8*)(Q + (size_t)(s0 + wv * 64 + qm * 16 + r16) * 1024
                                      + h * 64 + kk * 32 + g * 8);

  const f32x4 zero = {0.f, 0.f, 0.f, 0.f};
  f32x4 o[4][4];
  float mrun[4][4], lrun[4][4];
#pragma unroll
  for (int qm = 0; qm < 4; ++qm)
#pragma unroll
    for (int j = 0; j < 4; ++j){ mrun[qm][j] = -1e30f; lrun[qm][j] = 0.f; }
#pragma unroll
  for (int qm = 0; qm < 4; ++qm)
#pragma unroll
    for (int nd = 0; nd < 4; ++nd) o[qm][nd] = zero;

  const float cl2 = 0.125f * 1.44269504f;   // scale * log2(e)

  for (int kc = 0; kc < 4; ++kc){
    __syncthreads();   // prev-chunk readers done before LDS overwrite
    {
      const u16* ksrc = Kws + (size_t)(s0 + kc * 64 + r0) * 1024 + h * 64 + swz * 8;
      gld16(Kl + (wv << 9),        ksrc);
      gld16(Kl + 2048 + (wv << 9), ksrc + (size_t)32 * 1024);
      const u16* vsrc = Vt + vwin + (size_t)r0 * 256 + kc * 64 + swz * 8;
      gld16(Vl + (wv << 9),        vsrc);
      gld16(Vl + 2048 + (wv << 9), vsrc + 32 * 256);
    }
    __syncthreads();

    // QK^T for this 64-key chunk
    f32x4 sc[4][4];
#pragma unroll
    for (int qm = 0; qm < 4; ++qm)
#pragma unroll
      for (int nb = 0; nb < 4; ++nb) sc[qm][nb] = zero;
#pragma unroll
    for (int kk = 0; kk < 2; ++kk){
      bf16x8 kb[4];
#pragma unroll
      for (int nb = 0; nb < 4; ++nb){
        int rr = nb * 16 + r16;
        kb[nb] = *(const bf16x8*)((const char*)Kl + rr * 128
                                  + ((((kk << 2) | g) ^ (r16 & 7)) << 4));
      }
#pragma unroll
      for (int qm = 0; qm < 4; ++qm)
#pragma unroll
        for (int nb = 0; nb < 4; ++nb)
          sc[qm][nb] = mfma16(aq[qm][kk], kb[nb], sc[qm][nb]);
    }

    // online softmax + P -> LDS (bf16, swizzled)
#pragma unroll
    for (int qm = 0; qm < 4; ++qm){
#pragma unroll
      for (int j = 0; j < 4; ++j){
        float cm = fmaxf(fmaxf(sc[qm][0][j], sc[qm][1][j]),
                         fmaxf(sc[qm][2][j], sc[qm][3][j]));
        cm = fmaxf(cm, __shfl_xor(cm, 1));
        cm = fmaxf(cm, __shfl_xor(cm, 2));
        cm = fmaxf(cm, __shfl_xor(cm, 4));
        cm = fmaxf(cm, __shfl_xor(cm, 8));
        float mn = fmaxf(mrun[qm][j], cm);
        float fsc = __builtin_amdgcn_exp2f((mrun[qm][j] - mn) * cl2);
        mrun[qm][j] = mn;
        float rs = 0.f;
#pragma unroll
        for (int nb = 0; nb < 4; ++nb){
          float p = __builtin_amdgcn_exp2f((sc[qm][nb][j] - mn) * cl2);
          sc[qm][nb][j] = p;
          rs += p;
        }
        rs += __shfl_xor(rs, 1);
        rs += __shfl_xor(rs, 2);
        rs += __shfl_xor(rs, 4);
        rs += __shfl_xor(rs, 8);
        lrun[qm][j] = lrun[qm][j] * fsc + rs;
#pragma unroll
        for (int nd = 0; nd < 4; ++nd) o[qm][nd][j] *= fsc;
        int q = qm * 16 + g * 4 + j;
        char* pbase = (char*)Pl + (wv << 13) + q * 128;
#pragma unroll
        for (int nb = 0; nb < 4; ++nb){
          int k = nb * 16 + r16;
          *(u16*)(pbase + ((k & 7) * 2 + (((k >> 3) ^ (q & 7)) << 4))) = f2bf(sc[qm][nb][j]);
        }
      }
    }

    // PV: O += P[64q x 64k] * V[64k x 64d]
#pragma unroll
    for (int kc32 = 0; kc32 < 2; ++kc32){
      bf16x8 pa[4], vb[4];
#pragma unroll
      for (int qm = 0; qm < 4; ++qm){
        int q = qm * 16 + r16;
        pa[qm] = *(const bf16x8*)((const char*)Pl + (wv << 13) + q * 128
                                  + ((((kc32 << 2) | g) ^ (r16 & 7)) << 4));
      }
#pragma unroll
      for (int nd = 0; nd < 4; ++nd){
        int dd = nd * 16 + r16;
        vb[nd] = *(const bf16x8*)((const char*)Vl + dd * 128
                                  + ((((kc32 << 2) | g) ^ (r16 & 7)) << 4));
      }
#pragma unroll
      for (int qm = 0; qm < 4; ++qm)
#pragma unroll
        for (int nd = 0; nd < 4; ++nd)
          o[qm][nd] = mfma16(pa[qm], vb[nd], o[qm][nd]);
    }
  }

  // normalize + store (bf16, [B,S,H*D] layout)
#pragma unroll
  for (int qm = 0; qm < 4; ++qm){
#pragma unroll
    for (int j = 0; j < 4; ++j){
      float inv = 1.f / lrun[qm][j];
      int row = s0 + wv * 64 + qm * 16 + g * 4 + j;
#pragma unroll
      for (int nd = 0; nd < 4; ++nd)
        Oo[(size_t)row * 1024 + h * 64 + nd * 16 + r16] = f2bf(o[qm][nd][j] * inv);
    }
  }
}

// ---------------- launch ----------------
extern "C" void kernel_launch(void* const* d_in, const int* in_sizes, int n_in,
                              void* d_out, int out_size, void* d_ws, size_t ws_size,
                              hipStream_t stream)
{
  (void)in_sizes; (void)n_in; (void)out_size; (void)ws_size;
  const float* x  = (const float*)d_in[0];
  const float* Wq = (const float*)d_in[1];
  const float* bq = (const float*)d_in[2];
  const float* Wo = (const float*)d_in[3];
  const float* bo = (const float*)d_in[4];

  char* ws = (char*)d_ws;
  const size_t SZ = (size_t)16384 * 1024 * 2;          // 33.5 MB
  u16* xb  = (u16*)(ws);                               // x bf16, later reused for attn out
  u16* Vt  = (u16*)(ws + SZ);                          // V transposed per window
  u16* wqb = (u16*)(ws + 2 * SZ);                      // W_qkv bf16 (6.29 MB)
  u16* wob = (u16*)(ws + 2 * SZ + 6291456);            // W_out bf16 (2.1 MB)
  // Q,K staged in d_out (dead until final GEMM overwrites it)
  u16* Qws = (u16*)d_out;
  u16* Kws = (u16*)d_out + (size_t)16384 * 1024;

  cvt_bf16<<<2048, 256, 0, stream>>>(x,  xb,  16777216 / 4);
  cvt_bf16<<<768,  256, 0, stream>>>(Wq, wqb, 3145728 / 4);
  cvt_bf16<<<256,  256, 0, stream>>>(Wo, wob, 1048576 / 4);

  gemm_bt<0><<<dim3(12, 64), 512, 0, stream>>>(xb, wqb, bq, Qws, Kws, Vt, nullptr);

  attn_win<<<1024, 256, 0, stream>>>(Qws, Kws, Vt, xb);

  gemm_bt<1><<<dim3(4, 64), 512, 0, stream>>>(xb, wob, bo,
                                              nullptr, nullptr, nullptr,
                                              (float*)d_out);
}

// Round 3
// 278.283 us; speedup vs baseline: 1.1899x; 1.0613x over previous
//
#include <hip/hip_runtime.h>

typedef unsigned short u16;
typedef __bf16 bf16x8 __attribute__((ext_vector_type(8)));
typedef float f32x4 __attribute__((ext_vector_type(4)));
typedef u16 u16x4 __attribute__((ext_vector_type(4)));

#define DEVI static __device__ __forceinline__

DEVI u16 f2bf(float f){
  unsigned u = __float_as_uint(f);
  u += 0x7FFFu + ((u >> 16) & 1u);
  return (u16)(u >> 16);
}

DEVI f32x4 mfma16(bf16x8 a, bf16x8 b, f32x4 c){
  return __builtin_amdgcn_mfma_f32_16x16x32_bf16(a, b, c, 0, 0, 0);
}

DEVI void gld16(u16* lds, const u16* g){
  __builtin_amdgcn_global_load_lds(
      (const __attribute__((address_space(1))) void*)g,
      (__attribute__((address_space(3))) void*)lds, 16, 0, 0);
}

// ---------------- fp32 -> bf16 convert ----------------
__global__ void cvt_bf16(const float* __restrict__ s, u16* __restrict__ d, int n4){
  int i = blockIdx.x * blockDim.x + threadIdx.x;
  int stride = gridDim.x * blockDim.x;
  for (; i < n4; i += stride){
    float4 v = *(const float4*)(s + (size_t)i * 4);
    u16x4 o = { f2bf(v.x), f2bf(v.y), f2bf(v.z), f2bf(v.w) };
    *(u16x4*)(d + (size_t)i * 4) = o;
  }
}

// ---------------- GEMM: C = A * Bm^T + bias ----------------
// 256x256 tile, BK=64, 512 threads (8 waves 2Mx4N, each 128x64 out).
// 2 LDS buffers (128 KiB). 4 phases per K-tile, m201-style:
//   [ds_read subtile || stage] ; s_barrier ; lgkmcnt(0) ; 16 MFMA ; s_barrier
// Lead-2 staging into the CURRENT buffer: B region dead after ph0 (all B in
// regs), A region dead after ph1 -> stage t+2's B at ph1/ph2, A at ph2/ph3.
// vmcnt(8) once per tile boundary (never 0 in main loop).
// Swizzle: 16B-chunk ^= row&7 (row = 128B), linear gld_lds dest +
// inverse-swizzled global source + swizzled ds_read.
// MODE 0: QKV epilogue; MODE 1: fp32 + bias.
template<int MODE>
__global__ __launch_bounds__(512, 2)
void gemm_bt(const u16* __restrict__ A, const u16* __restrict__ Bm,
             const float* __restrict__ bias,
             u16* __restrict__ Qws, u16* __restrict__ Kws, u16* __restrict__ Vtws,
             float* __restrict__ Cf)
{
  constexpr int K = 1024;
  constexpr int NT = K / 64;                       // 16 K-tiles
  __shared__ __align__(16) u16 lds[2 * 32768];     // 128 KiB
  const int t = threadIdx.x;
  const int w = t >> 6, l = t & 63, g = l >> 4, r16 = l & 15;
  const int wm = w >> 2, wn = w & 3;

  // XCD-bijective block swizzle (nwg % 8 == 0 in both modes)
  constexpr int NBX = (MODE == 0) ? 12 : 4;
  constexpr int NWG = NBX * 64;
  const int orig = blockIdx.y * NBX + blockIdx.x;
  const int swzb = (orig & 7) * (NWG >> 3) + (orig >> 3);
  const int row0 = (swzb / NBX) * 256, col0 = (swzb % NBX) * 256;

  const f32x4 zero = {0.f, 0.f, 0.f, 0.f};
  f32x4 acc[8][4];
#pragma unroll
  for (int m = 0; m < 8; ++m)
#pragma unroll
    for (int n = 0; n < 4; ++n) acc[m][n] = zero;

  // ---- staging: thread t -> LDS 16B chunk t (linear within 8KB block-load j).
  // LDS row = j*64 + (t>>3), stored chunk-in-row = t&7; global logical chunk
  // = (t&7) ^ (row&7)  (inverse swizzle on the SOURCE, rule 21).
  const int rw = t >> 3;
  const int lcn = (t & 7) ^ (rw & 7);
  const u16* pA = A + (size_t)(row0 + rw) * K + lcn * 8;
  const u16* pB = Bm + (size_t)(col0 + rw) * K + lcn * 8;

  auto STAGE1 = [&](u16* sbase, int j, int kt){
    const u16* src = (j < 4) ? (pA + j * 65536 + kt) : (pB + (j - 4) * 65536 + kt);
    gld16(sbase + j * 4096, src);
  };

  // ---- reads: row stride 64 u16 (128B); chunk-in-row = ((ks*4+g) ^ (r16&7))
  auto LD_A = [&](const u16* base, int m, int ks) -> bf16x8 {
    return *(const bf16x8*)(base + (wm * 128 + m * 16 + r16) * 64
                            + ((((ks << 2) | g) ^ (r16 & 7)) << 3));
  };
  auto LD_B = [&](const u16* base, int n, int ks) -> bf16x8 {
    return *(const bf16x8*)(base + 16384 + (wn * 64 + n * 16 + r16) * 64
                            + ((((ks << 2) | g) ^ (r16 & 7)) << 3));
  };

  bf16x8 af[8][2], bfr[4][2];

  auto MFMA2 = [&](int m0){
    __builtin_amdgcn_s_setprio(1);
#pragma unroll
    for (int mm = 0; mm < 2; ++mm)
#pragma unroll
      for (int n = 0; n < 4; ++n)
#pragma unroll
        for (int ks = 0; ks < 2; ++ks)
          acc[m0 + mm][n] = mfma16(af[m0 + mm][ks], bfr[n][ks], acc[m0 + mm][n]);
    __builtin_amdgcn_s_setprio(0);
  };

  // mode: 2 = stage tile t+2 + vmcnt(8); 1 = no stage + vmcnt(0); 0 = tail
  auto TILE = [&](int buf, int kt2, int mode){
    const u16* base = lds + buf * 32768;
    u16* sbase = lds + buf * 32768 + w * 512;
    // ---- ph0: read af[0..1] + all B (12 reads); MFMA m0,m1
#pragma unroll
    for (int ks = 0; ks < 2; ++ks){
      af[0][ks] = LD_A(base, 0, ks);
      af[1][ks] = LD_A(base, 1, ks);
#pragma unroll
      for (int n = 0; n < 4; ++n) bfr[n][ks] = LD_B(base, n, ks);
    }
    __builtin_amdgcn_s_barrier();
    asm volatile("s_waitcnt lgkmcnt(0)" ::: "memory");
    __builtin_amdgcn_sched_barrier(0);
    MFMA2(0);
    __builtin_amdgcn_s_barrier();
    asm volatile("" ::: "memory");
    // ---- ph1: read af[2..7] (12 reads); stage B halves 0,1; MFMA m2,m3
#pragma unroll
    for (int m = 2; m < 8; ++m)
#pragma unroll
      for (int ks = 0; ks < 2; ++ks) af[m][ks] = LD_A(base, m, ks);
    if (mode == 2){ STAGE1(sbase, 4, kt2); STAGE1(sbase, 5, kt2); }
    __builtin_amdgcn_s_barrier();
    asm volatile("s_waitcnt lgkmcnt(0)" ::: "memory");
    __builtin_amdgcn_sched_barrier(0);
    MFMA2(2);
    __builtin_amdgcn_s_barrier();
    asm volatile("" ::: "memory");
    // ---- ph2: stage B halves 2,3 + A halves 0,1; MFMA m4,m5
    if (mode == 2){
      STAGE1(sbase, 6, kt2); STAGE1(sbase, 7, kt2);
      STAGE1(sbase, 0, kt2); STAGE1(sbase, 1, kt2);
    }
    __builtin_amdgcn_s_barrier();
    MFMA2(4);
    __builtin_amdgcn_s_barrier();
    asm volatile("" ::: "memory");
    // ---- ph3: stage A halves 2,3; MFMA m6,m7; boundary vmcnt
    if (mode == 2){ STAGE1(sbase, 2, kt2); STAGE1(sbase, 3, kt2); }
    __builtin_amdgcn_s_barrier();
    MFMA2(6);
    if (mode == 2)      asm volatile("s_waitcnt vmcnt(8)" ::: "memory");
    else if (mode == 1) asm volatile("s_waitcnt vmcnt(0)" ::: "memory");
    __builtin_amdgcn_s_barrier();
    asm volatile("" ::: "memory");
  };

  // ---- prologue: stage tiles 0 (buf0) and 1 (buf1)
#pragma unroll
  for (int j = 0; j < 8; ++j) STAGE1(lds + w * 512, j, 0);
#pragma unroll
  for (int j = 0; j < 8; ++j) STAGE1(lds + 32768 + w * 512, j, 64);
  asm volatile("s_waitcnt vmcnt(8)" ::: "memory");
  __builtin_amdgcn_s_barrier();
  asm volatile("" ::: "memory");

  for (int it = 0; it < (NT - 2) / 2; ++it){      // tiles 0..13
    TILE(0, (2 * it + 2) * 64, 2);
    TILE(1, (2 * it + 3) * 64, 2);
  }
  TILE(0, 0, 1);                                  // tile 14
  TILE(1, 0, 0);                                  // tile 15

  // ---- epilogue ----
  float bv[4];
#pragma unroll
  for (int nb = 0; nb < 4; ++nb) bv[nb] = bias[col0 + wn * 64 + nb * 16 + r16];

  if (MODE == 1){
#pragma unroll
    for (int m = 0; m < 8; ++m){
      int row = row0 + wm * 128 + m * 16 + g * 4;
#pragma unroll
      for (int nb = 0; nb < 4; ++nb){
        int n = col0 + wn * 64 + nb * 16 + r16;
#pragma unroll
        for (int j = 0; j < 4; ++j)
          Cf[(size_t)(row + j) * 1024 + n] = acc[m][nb][j] + bv[nb];
      }
    }
  } else {
    const int regn = col0 >> 10;   // uniform per block: 0=Q 1=K 2=V
    if (regn == 0){
#pragma unroll
      for (int m = 0; m < 8; ++m){
        int row = row0 + wm * 128 + m * 16 + g * 4;
#pragma unroll
        for (int nb = 0; nb < 4; ++nb){
          int n = col0 + wn * 64 + nb * 16 + r16;
#pragma unroll
          for (int j = 0; j < 4; ++j)
            Qws[(size_t)(row + j) * 1024 + n] = f2bf(acc[m][nb][j] + bv[nb]);
        }
      }
    } else if (regn == 1){
#pragma unroll
      for (int m = 0; m < 8; ++m){
        int row = row0 + wm * 128 + m * 16 + g * 4;
#pragma unroll
        for (int nb = 0; nb < 4; ++nb){
          int n = col0 + wn * 64 + nb * 16 + r16 - 1024;
#pragma unroll
          for (int j = 0; j < 4; ++j)
            Kws[(size_t)(row + j) * 1024 + n] = f2bf(acc[m][nb][j] + bv[nb]);
        }
      }
    } else {
      // V: store transposed per window: Vt[win][d][rr], win=((b*16+h)*16+wd)
#pragma unroll
      for (int m = 0; m < 8; ++m){
        int row = row0 + wm * 128 + m * 16 + g * 4;
        int bb = row >> 12, s = row & 4095;
        int wdw = s >> 8, rr = s & 255;      // rr multiple of 4
#pragma unroll
        for (int nb = 0; nb < 4; ++nb){
          int n2 = col0 + wn * 64 + nb * 16 + r16 - 2048;
          int hh = n2 >> 6, d = n2 & 63;
          int winw = (bb * 16 + hh) * 16 + wdw;
          u16x4 pk;
#pragma unroll
          for (int j = 0; j < 4; ++j) pk[j] = f2bf(acc[m][nb][j] + bv[nb]);
          *(u16x4*)(Vtws + (size_t)winw * 16384 + d * 256 + rr) = pk;
        }
      }
    }
  }
}

// ---------------- windowed attention ----------------
// 1 block = 1 (b,h,window). 4 waves x 64 q-rows. Online softmax over 4
// key-chunks of 64. K chunk LDS [64 r][64 d], V chunk LDS [64 d][64 r]
// (pre-transposed in global by GEMM1), both XOR-swizzled via pre-swizzled
// global_load_lds source. P round-trips through wave-private swizzled LDS.
__global__ __launch_bounds__(256, 1)
void attn_win(const u16* __restrict__ Q, const u16* __restrict__ Kws,
              const u16* __restrict__ Vt, u16* __restrict__ Oo)
{
  __shared__ __align__(16) u16 Kl[64 * 64];
  __shared__ __align__(16) u16 Vl[64 * 64];
  __shared__ __align__(16) u16 Pl[4 * 64 * 64];
  const int t = threadIdx.x;
  const int wv = t >> 6, l = t & 63, g = l >> 4, r16 = l & 15;
  const int win = blockIdx.x;
  const int b = win >> 8, h = (win >> 4) & 15, wd = win & 15;
  const int s0 = b * 4096 + wd * 256;
  const size_t vwin = (size_t)win * 16384;
  const int r0 = t >> 3, sl = t & 7;
  const int swz = sl ^ (r0 & 7);

  bf16x8 aq[4][2];
#pragma unroll
  for (int qm = 0; qm < 4; ++qm)
#pragma unroll
    for (int kk = 0; kk < 2; ++kk)
      aq[qm][kk] = *(const bf16x8*)(Q + (size_t)(s0 + wv * 64 + qm * 16 + r16) * 1024
                                      + h * 64 + kk * 32 + g * 8);

  const f32x4 zero = {0.f, 0.f, 0.f, 0.f};
  f32x4 o[4][4];
  float mrun[4][4], lrun[4][4];
#pragma unroll
  for (int qm = 0; qm < 4; ++qm)
#pragma unroll
    for (int j = 0; j < 4; ++j){ mrun[qm][j] = -1e30f; lrun[qm][j] = 0.f; }
#pragma unroll
  for (int qm = 0; qm < 4; ++qm)
#pragma unroll
    for (int nd = 0; nd < 4; ++nd) o[qm][nd] = zero;

  const float cl2 = 0.125f * 1.44269504f;   // scale * log2(e)

  for (int kc = 0; kc < 4; ++kc){
    __syncthreads();   // prev-chunk readers done before LDS overwrite
    {
      const u16* ksrc = Kws + (size_t)(s0 + kc * 64 + r0) * 1024 + h * 64 + swz * 8;
      gld16(Kl + (wv << 9),        ksrc);
      gld16(Kl + 2048 + (wv << 9), ksrc + (size_t)32 * 1024);
      const u16* vsrc = Vt + vwin + (size_t)r0 * 256 + kc * 64 + swz * 8;
      gld16(Vl + (wv << 9),        vsrc);
      gld16(Vl + 2048 + (wv << 9), vsrc + 32 * 256);
    }
    __syncthreads();

    // QK^T for this 64-key chunk
    f32x4 sc[4][4];
#pragma unroll
    for (int qm = 0; qm < 4; ++qm)
#pragma unroll
      for (int nb = 0; nb < 4; ++nb) sc[qm][nb] = zero;
#pragma unroll
    for (int kk = 0; kk < 2; ++kk){
      bf16x8 kb[4];
#pragma unroll
      for (int nb = 0; nb < 4; ++nb){
        int rr = nb * 16 + r16;
        kb[nb] = *(const bf16x8*)((const char*)Kl + rr * 128
                                  + ((((kk << 2) | g) ^ (r16 & 7)) << 4));
      }
#pragma unroll
      for (int qm = 0; qm < 4; ++qm)
#pragma unroll
        for (int nb = 0; nb < 4; ++nb)
          sc[qm][nb] = mfma16(aq[qm][kk], kb[nb], sc[qm][nb]);
    }

    // online softmax + P -> LDS (bf16, swizzled)
#pragma unroll
    for (int qm = 0; qm < 4; ++qm){
#pragma unroll
      for (int j = 0; j < 4; ++j){
        float cm = fmaxf(fmaxf(sc[qm][0][j], sc[qm][1][j]),
                         fmaxf(sc[qm][2][j], sc[qm][3][j]));
        cm = fmaxf(cm, __shfl_xor(cm, 1));
        cm = fmaxf(cm, __shfl_xor(cm, 2));
        cm = fmaxf(cm, __shfl_xor(cm, 4));
        cm = fmaxf(cm, __shfl_xor(cm, 8));
        float mn = fmaxf(mrun[qm][j], cm);
        float fsc = __builtin_amdgcn_exp2f((mrun[qm][j] - mn) * cl2);
        mrun[qm][j] = mn;
        float rs = 0.f;
#pragma unroll
        for (int nb = 0; nb < 4; ++nb){
          float p = __builtin_amdgcn_exp2f((sc[qm][nb][j] - mn) * cl2);
          sc[qm][nb][j] = p;
          rs += p;
        }
        rs += __shfl_xor(rs, 1);
        rs += __shfl_xor(rs, 2);
        rs += __shfl_xor(rs, 4);
        rs += __shfl_xor(rs, 8);
        lrun[qm][j] = lrun[qm][j] * fsc + rs;
#pragma unroll
        for (int nd = 0; nd < 4; ++nd) o[qm][nd][j] *= fsc;
        int q = qm * 16 + g * 4 + j;
        char* pbase = (char*)Pl + (wv << 13) + q * 128;
#pragma unroll
        for (int nb = 0; nb < 4; ++nb){
          int k = nb * 16 + r16;
          *(u16*)(pbase + ((k & 7) * 2 + (((k >> 3) ^ (q & 7)) << 4))) = f2bf(sc[qm][nb][j]);
        }
      }
    }

    // PV: O += P[64q x 64k] * V[64k x 64d]
#pragma unroll
    for (int kc32 = 0; kc32 < 2; ++kc32){
      bf16x8 pa[4], vb[4];
#pragma unroll
      for (int qm = 0; qm < 4; ++qm){
        int q = qm * 16 + r16;
        pa[qm] = *(const bf16x8*)((const char*)Pl + (wv << 13) + q * 128
                                  + ((((kc32 << 2) | g) ^ (r16 & 7)) << 4));
      }
#pragma unroll
      for (int nd = 0; nd < 4; ++nd){
        int dd = nd * 16 + r16;
        vb[nd] = *(const bf16x8*)((const char*)Vl + dd * 128
                                  + ((((kc32 << 2) | g) ^ (r16 & 7)) << 4));
      }
#pragma unroll
      for (int qm = 0; qm < 4; ++qm)
#pragma unroll
        for (int nd = 0; nd < 4; ++nd)
          o[qm][nd] = mfma16(pa[qm], vb[nd], o[qm][nd]);
    }
  }

  // normalize + store (bf16, [B,S,H*D] layout)
#pragma unroll
  for (int qm = 0; qm < 4; ++qm){
#pragma unroll
    for (int j = 0; j < 4; ++j){
      float inv = 1.f / lrun[qm][j];
      int row = s0 + wv * 64 + qm * 16 + g * 4 + j;
#pragma unroll
      for (int nd = 0; nd < 4; ++nd)
        Oo[(size_t)row * 1024 + h * 64 + nd * 16 + r16] = f2bf(o[qm][nd][j] * inv);
    }
  }
}

// ---------------- launch ----------------
extern "C" void kernel_launch(void* const* d_in, const int* in_sizes, int n_in,
                              void* d_out, int out_size, void* d_ws, size_t ws_size,
                              hipStream_t stream)
{
  (void)in_sizes; (void)n_in; (void)out_size; (void)ws_size;
  const float* x  = (const float*)d_in[0];
  const float* Wq = (const float*)d_in[1];
  const float* bq = (const float*)d_in[2];
  const float* Wo = (const float*)d_in[3];
  const float* bo = (const float*)d_in[4];

  char* ws = (char*)d_ws;
  const size_t SZ = (size_t)16384 * 1024 * 2;          // 33.5 MB
  u16* xb  = (u16*)(ws);                               // x bf16, later reused for attn out
  u16* Vt  = (u16*)(ws + SZ);                          // V transposed per window
  u16* wqb = (u16*)(ws + 2 * SZ);                      // W_qkv bf16 (6.29 MB)
  u16* wob = (u16*)(ws + 2 * SZ + 6291456);            // W_out bf16 (2.1 MB)
  // Q,K staged in d_out (dead until final GEMM overwrites it)
  u16* Qws = (u16*)d_out;
  u16* Kws = (u16*)d_out + (size_t)16384 * 1024;

  cvt_bf16<<<2048, 256, 0, stream>>>(x,  xb,  16777216 / 4);
  cvt_bf16<<<768,  256, 0, stream>>>(Wq, wqb, 3145728 / 4);
  cvt_bf16<<<256,  256, 0, stream>>>(Wo, wob, 1048576 / 4);

  gemm_bt<0><<<dim3(12, 64), 512, 0, stream>>>(xb, wqb, bq, Qws, Kws, Vt, nullptr);

  attn_win<<<1024, 256, 0, stream>>>(Qws, Kws, Vt, xb);

  gemm_bt<1><<<dim3(4, 64), 512, 0, stream>>>(xb, wob, bo,
                                              nullptr, nullptr, nullptr,
                                              (float*)d_out);
}